// Round 3
// baseline (339.236 us; speedup 1.0000x reference)
//
#include <hip/hip_runtime.h>

// Problem constants (match reference)
#define BATCH 8192
#define TSTEPS 200
#define FEAT 16
#define HID 32
#define GATES 128   // 4*HID, Keras order: i | f | cc | o
#define DOUT 60
#define ROWS 16     // batch rows per tile (one MFMA N-tile, transposed form)
#define TILES 2     // independent LSTM tiles per wave (ILP for latency hiding)
#define WROWS (ROWS * TILES)
#define HSTRIDE 40  // LDS h row stride in halves (final head pass only)

typedef __fp16 half2v __attribute__((ext_vector_type(2)));
typedef __fp16 half4v __attribute__((ext_vector_type(4)));
typedef __fp16 half8v __attribute__((ext_vector_type(8)));
typedef float  float4v __attribute__((ext_vector_type(4)));

// Weights/bias for i/f/o gates pre-scaled by -log2(e):
// sigmoid(x) = 1 / (1 + exp2(-log2e * x))
__device__ __forceinline__ float sig_pre(float v) {
    return __builtin_amdgcn_rcpf(1.0f + __builtin_amdgcn_exp2f(v));
}

__device__ __forceinline__ half2v pkrtz(float a, float b) {
    return __builtin_amdgcn_cvt_pkrtz(a, b);
}

__device__ __forceinline__ half4v pack4(float4 v) {
    half2v lo = pkrtz(v.x, v.y);
    half2v hi = pkrtz(v.z, v.w);
    half4v r;
    r[0] = lo[0]; r[1] = lo[1]; r[2] = hi[0]; r[3] = hi[1];
    return r;
}

// Permuted gate-column map (verified round 2). Tile tt (0..7) = gate-type
// (tt>>1: i,f,cc,o) x half (tt&1). Column m -> unit 8*(m>>2)+(m&3)+4*(tt&1).
// Lane (g,n16) owns D rows m=4g+r and emits h for units 8g+r / 8g+4+r of
// batch row n16 -- exactly its own next-step B-fragment k-range 8g..8g+7.
__device__ __forceinline__ int gcol(int tt, int m) {
    return 32 * (tt >> 1) + 8 * (m >> 2) + (m & 3) + 4 * (tt & 1);
}

// Register-resident persistent LSTM, TWO independent tiles per wave.
// Transposed compute: gates^T = U^T·h^T (8x mfma 16x16x32 per tile) and
// W^T·x^T (8x mfma 16x16x16 per tile, one step ahead). Stationary U/W/bias
// fragments are shared by both tiles. The two tiles' chains are independent,
// so tile-1 instructions fill tile-0's MFMA/trans latency stalls and vice
// versa -- the wave becomes issue-bound instead of latency-bound.
// Fragment layouts (gfx950, verified rounds 1-2; A/B role-symmetric):
//   16x16x32 A[m][k]: m=lane&15, k=(lane>>4)*8+j ; B[k][n]: n=lane&15, same k
//   16x16x16 A[m][k]: m=lane&15, k=(lane>>4)*4+j ; B[k][n]: n=lane&15, same k
//   D[m][n]: n=lane&15, m=(lane>>4)*4+r
__global__ __launch_bounds__(64, 1) void lstm_mfma(
    const float* __restrict__ x,    // [B, T, F]
    const float* __restrict__ W,    // [F, 128]
    const float* __restrict__ U,    // [H, 128]
    const float* __restrict__ bg,   // [128]
    const float* __restrict__ W1,   // [H, 60]
    const float* __restrict__ b1,   // [60]
    const float* __restrict__ W2,   // [H, 60]
    const float* __restrict__ b2,   // [60]
    float* __restrict__ out)        // [2 * B * 60] (long || lat)
{
    const int lane = threadIdx.x;   // 64-thread block = 1 wave
    const int n16  = lane & 15;     // batch row within tile
    const int g    = lane >> 4;     // k-quad / D-row-quad
    const int b0   = blockIdx.x * WROWS;

    __shared__ __align__(16) __fp16 hbuf[WROWS * HSTRIDE];  // head pass only

    // ---- stationary A-frags: U^T (K=32), W^T (K=16), bias (per D-row) ----
    half8v  bU[8];
    half4v  bW[8];
    float4v bias[8];
    #pragma unroll
    for (int tt = 0; tt < 8; tt++) {
        const float s = ((tt >> 1) == 2) ? 1.0f : -1.44269504088896340736f;
        const int colA = gcol(tt, n16);
        half8v u8;
        #pragma unroll
        for (int j = 0; j < 8; j++)
            u8[j] = (__fp16)(U[(8 * g + j) * GATES + colA] * s);
        bU[tt] = u8;
        half4v w4;
        #pragma unroll
        for (int j = 0; j < 4; j++)
            w4[j] = (__fp16)(W[(4 * g + j) * GATES + colA] * s);
        bW[tt] = w4;
        float4v bv;
        #pragma unroll
        for (int r = 0; r < 4; r++)
            bv[r] = bg[gcol(tt, 4 * g + r)] * s;
        bias[tt] = bv;
    }

    // x sources: tile p covers batch rows b0 + 16p + [0,16)
    const float* xrow0 = x + (size_t)(b0 + n16) * TSTEPS * FEAT + 4 * g;
    const float* xrow1 = x + (size_t)(b0 + ROWS + n16) * TSTEPS * FEAT + 4 * g;

    float4 xa0 = *reinterpret_cast<const float4*>(xrow0 + FEAT);       // x_1
    float4 xb0 = *reinterpret_cast<const float4*>(xrow0 + 2 * FEAT);   // x_2
    float4 xa1 = *reinterpret_cast<const float4*>(xrow1 + FEAT);
    float4 xb1 = *reinterpret_cast<const float4*>(xrow1 + 2 * FEAT);

    // accx(0) = bias + W^T·x_0^T for both tiles
    float4v accx0[8], accx1[8];
    {
        half4v a0 = pack4(*reinterpret_cast<const float4*>(xrow0));
        half4v a1 = pack4(*reinterpret_cast<const float4*>(xrow1));
        #pragma unroll
        for (int tt = 0; tt < 8; tt++) {
            accx0[tt] = __builtin_amdgcn_mfma_f32_16x16x16f16(
                bW[tt], a0, bias[tt], 0, 0, 0);
            accx1[tt] = __builtin_amdgcn_mfma_f32_16x16x16f16(
                bW[tt], a1, bias[tt], 0, 0, 0);
        }
    }

    union hUn { half8v v; half2v h2[4]; };
    hUn hB0, hB1;                              // h_t B-frags, register-local
    hB0.v = (half8v)(__fp16)0.f;
    hB1.v = (half8v)(__fp16)0.f;
    float cst0[2][4] = {{0.f, 0.f, 0.f, 0.f}, {0.f, 0.f, 0.f, 0.f}};
    float cst1[2][4] = {{0.f, 0.f, 0.f, 0.f}, {0.f, 0.f, 0.f, 0.f}};

    // Gate epilogue for one tile half-set; writes next-step h frag in place.
#define EPI(ACC, CST, HB)                                                     \
    _Pragma("unroll")                                                         \
    for (int hf = 0; hf < 2; hf++) {                                          \
        float hn[4];                                                          \
        _Pragma("unroll")                                                     \
        for (int r = 0; r < 4; r++) {                                         \
            float iv = sig_pre(ACC[0 + hf][r]);                               \
            float fv = sig_pre(ACC[2 + hf][r]);                               \
            float cc = ACC[4 + hf][r];                                        \
            float ov = sig_pre(ACC[6 + hf][r]);                               \
            float cn = fmaf(fv, CST[hf][r], iv * fmaxf(cc, 0.f));             \
            CST[hf][r] = cn;                                                  \
            hn[r] = ov * fmaxf(cn, 0.f);                                      \
        }                                                                     \
        HB.h2[2 * hf]     = pkrtz(hn[0], hn[1]);                              \
        HB.h2[2 * hf + 1] = pkrtz(hn[2], hn[3]);                              \
    }

    // One step for BOTH tiles. XN0/XN1 hold x_{T+1}; refilled with x_{T+3}.
    // All 16 h·U MFMAs issue first (both tiles), then next-step x·W MFMAs,
    // then the two independent epilogues interleave in the scheduler.
#define STEP2(XN0, XN1, T)                                                    \
    {                                                                         \
        float4v acc0[8], acc1[8];                                             \
        _Pragma("unroll")                                                     \
        for (int tt = 0; tt < 8; tt++)                                        \
            acc0[tt] = __builtin_amdgcn_mfma_f32_16x16x32_f16(                \
                bU[tt], hB0.v, accx0[tt], 0, 0, 0);                           \
        _Pragma("unroll")                                                     \
        for (int tt = 0; tt < 8; tt++)                                        \
            acc1[tt] = __builtin_amdgcn_mfma_f32_16x16x32_f16(                \
                bU[tt], hB1.v, accx1[tt], 0, 0, 0);                           \
        if ((T) + 1 < TSTEPS) {                                               \
            half4v ax0 = pack4(XN0);                                          \
            half4v ax1 = pack4(XN1);                                          \
            _Pragma("unroll")                                                 \
            for (int tt = 0; tt < 8; tt++) {                                  \
                accx0[tt] = __builtin_amdgcn_mfma_f32_16x16x16f16(            \
                    bW[tt], ax0, bias[tt], 0, 0, 0);                          \
                accx1[tt] = __builtin_amdgcn_mfma_f32_16x16x16f16(            \
                    bW[tt], ax1, bias[tt], 0, 0, 0);                          \
            }                                                                 \
        }                                                                     \
        if ((T) + 3 < TSTEPS) {                                               \
            XN0 = *reinterpret_cast<const float4*>(                           \
                xrow0 + (size_t)((T) + 3) * FEAT);                            \
            XN1 = *reinterpret_cast<const float4*>(                           \
                xrow1 + (size_t)((T) + 3) * FEAT);                            \
        }                                                                     \
        EPI(acc0, cst0, hB0)                                                  \
        EPI(acc1, cst1, hB1)                                                  \
    }

    for (int t = 0; t < TSTEPS; t += 2) {
        STEP2(xa0, xa1, t);
        STEP2(xb0, xb1, t + 1);
    }
#undef STEP2
#undef EPI

    // ---- stage h_T to LDS (once), then heads: out = h_T @ W1/W2 + b ----
    *reinterpret_cast<half8v*>(&hbuf[n16 * HSTRIDE + 8 * g]) = hB0.v;
    *reinterpret_cast<half8v*>(&hbuf[(ROWS + n16) * HSTRIDE + 8 * g]) = hB1.v;
    __builtin_amdgcn_wave_barrier();   // in-wave DS ordering covers the reads

    for (int idx = lane; idx < WROWS * DOUT; idx += 64) {
        const int row = idx / DOUT;
        const int d   = idx - row * DOUT;
        float s1 = b1[d], s2 = b2[d];
        #pragma unroll 8
        for (int k = 0; k < HID; k++) {
            float hv = (float)hbuf[row * HSTRIDE + k];
            s1 = fmaf(hv, W1[k * DOUT + d], s1);
            s2 = fmaf(hv, W2[k * DOUT + d], s2);
        }
        out[(size_t)(b0 + row) * DOUT + d] = s1;
        out[(size_t)BATCH * DOUT + (size_t)(b0 + row) * DOUT + d] = s2;
    }
}

extern "C" void kernel_launch(void* const* d_in, const int* in_sizes, int n_in,
                              void* d_out, int out_size, void* d_ws, size_t ws_size,
                              hipStream_t stream) {
    const float* x  = (const float*)d_in[0];
    const float* W  = (const float*)d_in[1];
    const float* U  = (const float*)d_in[2];
    const float* bg = (const float*)d_in[3];
    const float* W1 = (const float*)d_in[4];
    const float* b1 = (const float*)d_in[5];
    const float* W2 = (const float*)d_in[6];
    const float* b2 = (const float*)d_in[7];
    float* out = (float*)d_out;

    dim3 grid(BATCH / WROWS);   // 256 blocks x 1 wave, 2 tiles per wave
    dim3 block(64);
    lstm_mfma<<<grid, block, 0, stream>>>(x, W, U, bg, W1, b1, W2, b2, out);
}

// Round 4
// 240.192 us; speedup vs baseline: 1.4124x; 1.4124x over previous
//
#include <hip/hip_runtime.h>

// Problem constants (match reference)
#define BATCH 8192
#define TSTEPS 200
#define FEAT 16
#define HID 32
#define GATES 128   // 4*HID, Keras order: i | f | cc | o
#define DOUT 60
#define ROWS 16     // batch rows per wave (one MFMA N-tile, transposed form)
#define HSTRIDE 40  // LDS h row stride in halves (final head pass only)

typedef __fp16 half2v __attribute__((ext_vector_type(2)));
typedef __fp16 half4v __attribute__((ext_vector_type(4)));
typedef __fp16 half8v __attribute__((ext_vector_type(8)));
typedef float  float4v __attribute__((ext_vector_type(4)));

__device__ __forceinline__ half2v pkrtz(float a, float b) {
    return __builtin_amdgcn_cvt_pkrtz(a, b);
}

__device__ __forceinline__ half4v pack4(float4 v) {
    half2v lo = pkrtz(v.x, v.y);
    half2v hi = pkrtz(v.z, v.w);
    half4v r;
    r[0] = lo[0]; r[1] = lo[1]; r[2] = hi[0]; r[3] = hi[1];
    return r;
}

// Permuted gate-column map (verified round 2). Tile tt (0..7) = gate-type
// (tt>>1: i,f,cc,o) x half (tt&1). Column m -> unit 8*(m>>2)+(m&3)+4*(tt&1).
// Lane (g,n16) owns D rows m=4g+r and emits h for units 8g+r / 8g+4+r of
// batch row n16 -- exactly its own next-step B-fragment k-range 8g..8g+7.
__device__ __forceinline__ int gcol(int tt, int m) {
    return 32 * (tt >> 1) + 8 * (m >> 2) + (m & 3) + 4 * (tt & 1);
}

union hUn { half8v v; half2v h2[4]; };

// One LSTM step, fully register-local (R2 structure).
// Gates i,f,o arrive pre-scaled by -log2(e): sig = 1/(1 + exp2(z~)).
// Trans-minimized epilogue (48 -> 32 trans/step):
//   per elem: d_i=1+e_i, d_f=1+e_f, d_o=1+e_o
//   c' = (c*d_i + relu(cc)*d_f) / (d_i*d_f)      [i/f rcps merged]
//   paired batch-inverse over r-neighbors for both c- and o-denominators:
//   Q=rcp(d0*d1); x0/d0 = x0*(d1*Q); x1/d1 = x1*(d0*Q)
// DO_XW/DO_LOAD are compile-time -> main loop body is one basic block.
template <bool DO_XW, bool DO_LOAD, int LOFF>
__device__ __forceinline__ void lstm_step(
    float4& XN, const float* xp,
    const half8v (&bU)[8], const half4v (&bW)[8], const float4v (&bias)[8],
    float4v (&accx)[8], hUn& hB, float (&cst)[2][4])
{
    float4v acc[8];
    #pragma unroll
    for (int tt = 0; tt < 8; tt++)
        acc[tt] = __builtin_amdgcn_mfma_f32_16x16x32_f16(
            bU[tt], hB.v, accx[tt], 0, 0, 0);

    if (DO_XW) {
        half4v ax = pack4(XN);
        #pragma unroll
        for (int tt = 0; tt < 8; tt++)
            accx[tt] = __builtin_amdgcn_mfma_f32_16x16x16f16(
                bW[tt], ax, bias[tt], 0, 0, 0);
    }
    if (DO_LOAD)
        XN = *reinterpret_cast<const float4*>(xp + LOFF);

    // ---- phase 1: all exponentials (trans pipe back-to-back) ----
    float ei[2][4], ef[2][4], eo[2][4];
    #pragma unroll
    for (int hf = 0; hf < 2; hf++)
        #pragma unroll
        for (int r = 0; r < 4; r++) {
            ei[hf][r] = __builtin_amdgcn_exp2f(acc[0 + hf][r]);
            ef[hf][r] = __builtin_amdgcn_exp2f(acc[2 + hf][r]);
            eo[hf][r] = __builtin_amdgcn_exp2f(acc[6 + hf][r]);
        }

    // ---- phase 2: denominators + numerators (full-rate VALU) ----
    float dd[2][4], num[2][4], dov[2][4];
    #pragma unroll
    for (int hf = 0; hf < 2; hf++)
        #pragma unroll
        for (int r = 0; r < 4; r++) {
            float di = 1.0f + ei[hf][r];
            float df = 1.0f + ef[hf][r];
            dov[hf][r] = 1.0f + eo[hf][r];
            float rc = fmaxf(acc[4 + hf][r], 0.0f);
            num[hf][r] = fmaf(cst[hf][r], di, rc * df);
            dd[hf][r]  = di * df;
        }

    // ---- phase 3: paired reciprocals + state update + pack ----
    #pragma unroll
    for (int hf = 0; hf < 2; hf++)
        #pragma unroll
        for (int p = 0; p < 2; p++) {
            const int r0 = 2 * p, r1 = 2 * p + 1;
            float Q  = __builtin_amdgcn_rcpf(dd[hf][r0] * dd[hf][r1]);
            float c0 = num[hf][r0] * (dd[hf][r1] * Q);
            float c1 = num[hf][r1] * (dd[hf][r0] * Q);
            cst[hf][r0] = c0;
            cst[hf][r1] = c1;
            float Qo = __builtin_amdgcn_rcpf(dov[hf][r0] * dov[hf][r1]);
            float h0 = fmaxf(c0, 0.0f) * (dov[hf][r1] * Qo);
            float h1 = fmaxf(c1, 0.0f) * (dov[hf][r0] * Qo);
            hB.h2[2 * hf + p] = pkrtz(h0, h1);
        }
}

__global__ __launch_bounds__(64, 1) void lstm_mfma(
    const float* __restrict__ x,    // [B, T, F]
    const float* __restrict__ W,    // [F, 128]
    const float* __restrict__ U,    // [H, 128]
    const float* __restrict__ bg,   // [128]
    const float* __restrict__ W1,   // [H, 60]
    const float* __restrict__ b1,   // [60]
    const float* __restrict__ W2,   // [H, 60]
    const float* __restrict__ b2,   // [60]
    float* __restrict__ out)        // [2 * B * 60] (long || lat)
{
    const int lane = threadIdx.x;   // 64-thread block = 1 wave
    const int n16  = lane & 15;     // batch row within tile
    const int g    = lane >> 4;     // k-quad / D-row-quad
    const int b0   = blockIdx.x * ROWS;

    __shared__ __align__(16) __fp16 hbuf[ROWS * HSTRIDE];  // head pass only

    // ---- stationary A-frags: U^T (K=32), W^T (K=16), bias (per D-row) ----
    half8v  bU[8];
    half4v  bW[8];
    float4v bias[8];
    #pragma unroll
    for (int tt = 0; tt < 8; tt++) {
        const float s = ((tt >> 1) == 2) ? 1.0f : -1.44269504088896340736f;
        const int colA = gcol(tt, n16);
        half8v u8;
        #pragma unroll
        for (int j = 0; j < 8; j++)
            u8[j] = (__fp16)(U[(8 * g + j) * GATES + colA] * s);
        bU[tt] = u8;
        half4v w4;
        #pragma unroll
        for (int j = 0; j < 4; j++)
            w4[j] = (__fp16)(W[(4 * g + j) * GATES + colA] * s);
        bW[tt] = w4;
        float4v bv;
        #pragma unroll
        for (int r = 0; r < 4; r++)
            bv[r] = bg[gcol(tt, 4 * g + r)] * s;
        bias[tt] = bv;
    }

    // x source: lane reads x[b0+n16][t][4g .. 4g+3] (B-frag of x^T)
    const float* xrow = x + (size_t)(b0 + n16) * TSTEPS * FEAT + 4 * g;

    float4 xf0 = *reinterpret_cast<const float4*>(xrow + FEAT);        // x_1
    float4 xf1 = *reinterpret_cast<const float4*>(xrow + 2 * FEAT);    // x_2

    // accx(0) = bias + W^T·x_0^T
    float4v accx[8];
    {
        half4v a0 = pack4(*reinterpret_cast<const float4*>(xrow));
        #pragma unroll
        for (int tt = 0; tt < 8; tt++)
            accx[tt] = __builtin_amdgcn_mfma_f32_16x16x16f16(
                bW[tt], a0, bias[tt], 0, 0, 0);
    }

    hUn hB;
    hB.v = (half8v)(__fp16)0.f;                    // h_0 = 0
    float cst[2][4] = {{0.f, 0.f, 0.f, 0.f}, {0.f, 0.f, 0.f, 0.f}};

    // Branch-free main loop: steps 0..195 (98 two-step iterations).
    // Invariant at iteration start (step t): xf0 = x_{t+1}, xf1 = x_{t+2},
    // accx = bias + W^T x_t, xp = &x_t. Loads hit constant imm offsets.
    const float* xp = xrow;
    for (int it = 0; it < (TSTEPS - 4) / 2; ++it) {
        lstm_step<true, true, 3 * FEAT>(xf0, xp, bU, bW, bias, accx, hB, cst);
        lstm_step<true, true, 4 * FEAT>(xf1, xp, bU, bW, bias, accx, hB, cst);
        xp += 2 * FEAT;
    }
    // Peeled tail: steps 196..199 (xp == &x_196; xf0=x_197, xf1=x_198)
    lstm_step<true, true, 3 * FEAT>(xf0, xp, bU, bW, bias, accx, hB, cst); // 196, loads x_199
    lstm_step<true, false, 0>(xf1, xp, bU, bW, bias, accx, hB, cst);       // 197
    lstm_step<true, false, 0>(xf0, xp, bU, bW, bias, accx, hB, cst);       // 198 (xf0 = x_199)
    lstm_step<false, false, 0>(xf1, xp, bU, bW, bias, accx, hB, cst);      // 199

    // ---- stage h_T to LDS (once), then heads: out = h_T @ W1/W2 + b ----
    // lane holds h_T for (row n16, units 8g..8g+7): contiguous 16B store.
    *reinterpret_cast<half8v*>(&hbuf[n16 * HSTRIDE + 8 * g]) = hB.v;
    __builtin_amdgcn_wave_barrier();   // in-wave DS ordering covers the reads

    for (int idx = lane; idx < ROWS * DOUT; idx += 64) {
        const int row = idx / DOUT;
        const int d   = idx - row * DOUT;
        float s1 = b1[d], s2 = b2[d];
        #pragma unroll 8
        for (int k = 0; k < HID; k++) {
            float hv = (float)hbuf[row * HSTRIDE + k];
            s1 = fmaf(hv, W1[k * DOUT + d], s1);
            s2 = fmaf(hv, W2[k * DOUT + d], s2);
        }
        out[(size_t)(b0 + row) * DOUT + d] = s1;
        out[(size_t)BATCH * DOUT + (size_t)(b0 + row) * DOUT + d] = s2;
    }
}

extern "C" void kernel_launch(void* const* d_in, const int* in_sizes, int n_in,
                              void* d_out, int out_size, void* d_ws, size_t ws_size,
                              hipStream_t stream) {
    const float* x  = (const float*)d_in[0];
    const float* W  = (const float*)d_in[1];
    const float* U  = (const float*)d_in[2];
    const float* bg = (const float*)d_in[3];
    const float* W1 = (const float*)d_in[4];
    const float* b1 = (const float*)d_in[5];
    const float* W2 = (const float*)d_in[6];
    const float* b2 = (const float*)d_in[7];
    float* out = (float*)d_out;

    dim3 grid(BATCH / ROWS);   // 512 blocks x 1 wave, fully independent
    dim3 block(64);
    lstm_mfma<<<grid, block, 0, stream>>>(x, W, U, bg, W1, b1, W2, b2, out);
}